// Round 5
// baseline (886.477 us; speedup 1.0000x reference)
//
#include <hip/hip_runtime.h>

typedef __bf16 bf16;
typedef __bf16 bf16x8 __attribute__((ext_vector_type(8)));
typedef float f32x4 __attribute__((ext_vector_type(4)));

#define MFMA16(a,b,c) __builtin_amdgcn_mfma_f32_16x16x32_bf16(a,b,c,0,0,0)

#define N_Q   4096
#define DFEAT 512
#define KQ    8192
#define NLAB  128
#define NHEAD 8

// ---------------- workspace layout (bytes) ----------------
#define MBv (1024ull*1024ull)
#define OFF_COUNTS 0ull
#define OFF_MODE   512ull
#define OFF_FLAGS  1024ull
#define OFF_SEL    (64ull*1024ull)
#define OFF_FQ1    (1ull*MBv)
#define OFF_FQ2    (9ull*MBv)
#define OFF_LQ1    (17ull*MBv)
#define OFF_LQ2    (19ull*MBv)
#define OFF_Q1     (21ull*MBv)
#define OFF_Q2     (25ull*MBv)
#define OFF_K1     (29ull*MBv)  // 16384x512 bf16 (both streams)
#define OFF_WQT    (45ull*MBv)
#define OFF_WKT    (46ull*MBv)
#define OFF_WOT    (47ull*MBv)
#define OFF_VWT    (48ull*MBv)  // 128x16384 bf16 (VW^T, kv-swizzled)
#define OFF_ACC    (52ull*MBv)  // 2x4096x128 f32 = 4MB
#define OFF_L      (56ull*MBv)  // 2x8x4096 f32 = 256KB

// ---------------- dtype-agnostic loads ----------------
__device__ __forceinline__ float loads(const void* p, size_t i, int f32m) {
    return f32m ? ((const float*)p)[i] : (float)((const bf16*)p)[i];
}
__device__ __forceinline__ bf16x8 load8(const void* p, size_t i, int f32m) {
    bf16x8 r;
    if (f32m) {
        const float4* q = (const float4*)((const float*)p + i);
        float4 f0 = q[0], f1 = q[1];
        r[0] = (bf16)f0.x; r[1] = (bf16)f0.y; r[2] = (bf16)f0.z; r[3] = (bf16)f0.w;
        r[4] = (bf16)f1.x; r[5] = (bf16)f1.y; r[6] = (bf16)f1.z; r[7] = (bf16)f1.w;
    } else {
        r = *(const bf16x8*)((const bf16*)p + i);
    }
    return r;
}

// ---------------- dtype detector ----------------
__global__ void detect_kernel(const void* probe, int* mode) {
    const unsigned short* u = (const unsigned short*)probe;
    int t = threadIdx.x;
    int bad = 0;
    for (int i = t; i < 2048; i += 256) {
        unsigned short v = u[2 * i];
        int e = (v >> 7) & 0xFF;
        if (e > 140 || (e < 60 && e != 0)) bad++;
    }
    __shared__ int sb[256];
    sb[t] = bad;
    __syncthreads();
    for (int off = 128; off; off >>= 1) {
        if (t < off) sb[t] += sb[t + off];
        __syncthreads();
    }
    if (t == 0) mode[0] = (sb[0] > 200) ? 1 : 0;
}

// ---------------- flag: row-max > 0.95 ----------------
__global__ void flag_kernel(const void* __restrict__ ulb1, const void* __restrict__ ulb2,
                            int* __restrict__ flags, const int* __restrict__ modep) {
    int f32m = *modep;
    int row = blockIdx.x, s = blockIdx.y, t = threadIdx.x; // 64 threads
    const void* p = s ? ulb2 : ulb1;
    size_t base = (size_t)row * NLAB;
    float m = fmaxf(loads(p, base + t, f32m), loads(p, base + t + 64, f32m));
    #pragma unroll
    for (int off = 32; off; off >>= 1) m = fmaxf(m, __shfl_xor(m, off));
    if (t == 0) flags[s * N_Q + row] = (m > 0.95f) ? 1 : 0;
}

// ---------------- scan: stable compaction ----------------
__global__ void scan_kernel(const int* __restrict__ flags, int* __restrict__ sel,
                            int* __restrict__ counts) {
    int s = blockIdx.x, t = threadIdx.x; // 1024 threads
    const int* f = flags + s * N_Q;
    int* selp = sel + s * N_Q;
    __shared__ int ls[1024];
    int f0 = f[t*4], f1 = f[t*4+1], f2 = f[t*4+2], f3 = f[t*4+3];
    int local = f0 + f1 + f2 + f3;
    ls[t] = local;
    __syncthreads();
    for (int off = 1; off < 1024; off <<= 1) {
        int v = (t >= off) ? ls[t - off] : 0;
        __syncthreads();
        ls[t] += v;
        __syncthreads();
    }
    int pos = ls[t] - local;
    if (f0) selp[pos++] = t*4;
    if (f1) selp[pos++] = t*4+1;
    if (f2) selp[pos++] = t*4+2;
    if (f3) selp[pos++] = t*4+3;
    if (t == 1023) counts[s] = ls[1023];
}

// ---------------- build queues ----------------
__global__ void buildq_kernel(const void* __restrict__ anchor, const void* __restrict__ positive,
                              const void* __restrict__ lbfeat, const void* __restrict__ lboh,
                              const void* __restrict__ ulb1, const void* __restrict__ ulb2,
                              const void* __restrict__ fq1i, const void* __restrict__ fq2i,
                              const void* __restrict__ lq1i, const void* __restrict__ lq2i,
                              const int* __restrict__ sel, const int* __restrict__ counts,
                              bf16* __restrict__ fq1o, bf16* __restrict__ fq2o,
                              bf16* __restrict__ lq1o, bf16* __restrict__ lq2o,
                              const int* __restrict__ modep) {
    int f32m = *modep;
    int i = blockIdx.x, s = blockIdx.y, t = threadIdx.x; // 128 threads
    int C = counts[s];
    const void *fb, *lb;
    size_t frow, lrow;
    if (i < C) {
        int r = sel[s * N_Q + i];
        fb = s ? positive : anchor; frow = r;
        lb = s ? ulb2 : ulb1;       lrow = r;
    } else if (i < C + 512) {
        int r = i - C + s * 512;
        fb = lbfeat; frow = r;
        lb = lboh;   lrow = r;
    } else {
        int r = i - C - 512;
        fb = s ? fq2i : fq1i; frow = r;
        lb = s ? lq2i : lq1i; lrow = r;
    }
    bf16* fd = (s ? fq2o : fq1o) + (size_t)i * DFEAT;
    bf16* ld = (s ? lq2o : lq1o) + (size_t)i * NLAB;
    if (t < 64)      *(bf16x8*)&fd[t * 8]        = load8(fb, frow * DFEAT + (size_t)t * 8, f32m);
    else if (t < 80) *(bf16x8*)&ld[(t - 64) * 8] = load8(lb, lrow * NLAB + (size_t)(t - 64) * 8, f32m);
}

// ---------------- fused transposes (z: 0=Wq, 1=Wk, 2=Wo) ----------------
__global__ void transpose_kernel(const void* __restrict__ Wq, const void* __restrict__ Wk,
                                 const void* __restrict__ Wo,
                                 bf16* __restrict__ Tq, bf16* __restrict__ Tk, bf16* __restrict__ To,
                                 const int* __restrict__ modep) {
    int z = blockIdx.z;
    const void* W = (z == 0) ? Wq : (z == 1) ? Wk : Wo;
    bf16* T = (z == 0) ? Tq : (z == 1) ? Tk : To;
    int n = (z == 2) ? 128 : 512;
    if (z == 2 && (blockIdx.x >= 4 || blockIdx.y >= 4)) return;
    int f32m = *modep;
    __shared__ bf16 tile[32][33];
    int bx = blockIdx.x * 32, by = blockIdx.y * 32;
    int tx = threadIdx.x & 31, ty = threadIdx.x >> 5;
    for (int r = ty; r < 32; r += 8) tile[r][tx] = (bf16)loads(W, (size_t)(by + r) * n + bx + tx, f32m);
    __syncthreads();
    for (int r = ty; r < 32; r += 8) T[(size_t)(bx + r) * n + by + tx] = tile[tx][r];
}

// ---------------- NT GEMM: C = alpha * A @ Bt^T; optional kv-swizzle; optional batch-2 ----------------
__launch_bounds__(256, 2)
__global__ void gemm_nt(const void* __restrict__ A, const void* __restrict__ A2,
                        const bf16* __restrict__ B,
                        bf16* __restrict__ C, bf16* __restrict__ C2,
                        int M, int N, int Kd, float alpha,
                        const int* __restrict__ modep, int a_raw, int swz) {
    int f32m = a_raw ? *modep : 0;
    if (blockIdx.z) { A = A2; C = C2; }
    __shared__ __align__(16) bf16 As[128 * 72];
    __shared__ __align__(16) bf16 Bs[128 * 72];
    int m0 = blockIdx.x * 128, n0 = blockIdx.y * 128;
    int t = threadIdx.x, lane = t & 63, wid = t >> 6;
    int quad = lane >> 4, l15 = lane & 15;
    int wrow = (wid >> 1) * 64, wcol = (wid & 1) * 64;
    int srow = t >> 1, sseg = t & 1;
    f32x4 acc[4][4] = {};
    for (int k0 = 0; k0 < Kd; k0 += 32) {
        __syncthreads();
        bf16x8 a0 = load8(A, (size_t)(m0 + srow) * Kd + k0 + sseg * 8, f32m);
        bf16x8 a1 = load8(A, (size_t)(m0 + srow) * Kd + k0 + (sseg + 2) * 8, f32m);
        const uint4* gb = (const uint4*)(B + (size_t)(n0 + srow) * Kd + k0);
        uint4 b0 = gb[sseg], b1 = gb[sseg + 2];
        *(bf16x8*)&As[srow * 72 + sseg * 8]       = a0;
        *(bf16x8*)&As[srow * 72 + (sseg + 2) * 8] = a1;
        *(uint4*)&Bs[srow * 72 + sseg * 8]        = b0;
        *(uint4*)&Bs[srow * 72 + (sseg + 2) * 8]  = b1;
        __syncthreads();
        bf16x8 af[4], bfr[4];
        #pragma unroll
        for (int mt = 0; mt < 4; mt++) af[mt]  = *(const bf16x8*)&As[(wrow + mt*16 + l15) * 72 + quad * 8];
        #pragma unroll
        for (int nt = 0; nt < 4; nt++) bfr[nt] = *(const bf16x8*)&Bs[(wcol + nt*16 + l15) * 72 + quad * 8];
        #pragma unroll
        for (int mt = 0; mt < 4; mt++)
            #pragma unroll
            for (int nt = 0; nt < 4; nt++)
                acc[mt][nt] = MFMA16(af[mt], bfr[nt], acc[mt][nt]);
    }
    #pragma unroll
    for (int mt = 0; mt < 4; mt++)
        #pragma unroll
        for (int nt = 0; nt < 4; nt++)
            #pragma unroll
            for (int r = 0; r < 4; r++) {
                int row = m0 + wrow + mt*16 + quad*4 + r;
                int col = n0 + wcol + nt*16 + l15;
                if (swz) col = (col & ~31) | (((col & 12) << 1) | ((col & 16) >> 2) | (col & 3));
                C[(size_t)row * N + col] = (bf16)(acc[mt][nt][r] * alpha);
            }
}

// ---------------- pass 1: softmax denominators l[s][h][q] ----------------
__launch_bounds__(128, 4)
__global__ void pass1_kernel(const bf16* __restrict__ q1, const bf16* __restrict__ q2,
                             const bf16* __restrict__ kbase, float* __restrict__ lbuf) {
    __shared__ __align__(16) bf16 Kt[2][64 * 72];
    int qb = blockIdx.x >> 2, kvs = blockIdx.x & 3, h = blockIdx.y, s = blockIdx.z;
    const bf16* Q  = s ? q2 : q1;
    const bf16* Kp = kbase + (size_t)s * KQ * DFEAT + h * 64;
    int t = threadIdx.x, lane = t & 63, wid = t >> 6;  // 2 waves
    int quad = lane >> 4, l15 = lane & 15;
    int qbase = qb * 128 + wid * 64;

    bf16x8 qf[4][2];
    #pragma unroll
    for (int mt = 0; mt < 4; mt++)
        #pragma unroll
        for (int kc = 0; kc < 2; kc++)
            qf[mt][kc] = *(const bf16x8*)(Q + (size_t)(qbase + mt*16 + l15) * DFEAT + h*64 + kc*32 + quad*8);

    int kr = t >> 1, ks = t & 1;
    const bf16* kg = Kp + (size_t)(kvs * 2048 + kr) * DFEAT + ks * 32;
    bf16* kw0 = &Kt[0][kr * 72 + ks * 32];
    {
        uint4 a0 = *(const uint4*)kg, a1 = *(const uint4*)(kg + 8);
        uint4 a2 = *(const uint4*)(kg + 16), a3 = *(const uint4*)(kg + 24);
        *(uint4*)kw0 = a0; *(uint4*)(kw0 + 8) = a1;
        *(uint4*)(kw0 + 16) = a2; *(uint4*)(kw0 + 24) = a3;
    }
    __syncthreads();

    float lsum[4] = {0.f, 0.f, 0.f, 0.f};
    for (int it = 0; it < 32; it++) {
        int p = it & 1;
        uint4 n0, n1, n2, n3;
        bool more = (it + 1 < 32);
        if (more) {
            const bf16* kn = kg + (size_t)(it + 1) * 64 * DFEAT;
            n0 = *(const uint4*)kn; n1 = *(const uint4*)(kn + 8);
            n2 = *(const uint4*)(kn + 16); n3 = *(const uint4*)(kn + 24);
        }
        const bf16* Kb = &Kt[p][0];
        #pragma unroll
        for (int nt = 0; nt < 4; nt++) {
            bf16x8 k0 = *(const bf16x8*)&Kb[(nt*16 + l15) * 72 + quad * 8];
            bf16x8 k1 = *(const bf16x8*)&Kb[(nt*16 + l15) * 72 + 32 + quad * 8];
            #pragma unroll
            for (int mt = 0; mt < 4; mt++) {
                f32x4 a = {};
                a = MFMA16(k0, qf[mt][0], a);
                a = MFMA16(k1, qf[mt][1], a);
                lsum[mt] += exp2f(a[0]) + exp2f(a[1]) + exp2f(a[2]) + exp2f(a[3]);
            }
        }
        if (more) {
            bf16* kw = kw0 + (p ^ 1) * (64 * 72);
            *(uint4*)kw = n0; *(uint4*)(kw + 8) = n1;
            *(uint4*)(kw + 16) = n2; *(uint4*)(kw + 24) = n3;
        }
        __syncthreads();
    }
    #pragma unroll
    for (int mt = 0; mt < 4; mt++) {
        lsum[mt] += __shfl_xor(lsum[mt], 16);
        lsum[mt] += __shfl_xor(lsum[mt], 32);
    }
    if (quad == 0) {
        #pragma unroll
        for (int mt = 0; mt < 4; mt++)
            atomicAdd(&lbuf[(((size_t)s * NHEAD + h) << 12) + qbase + mt*16 + l15], lsum[mt]);
    }
}

// ---------------- pass 2: head-fused Pbar + single PV ----------------
__launch_bounds__(256, 2)
__global__ void pass2_kernel(const bf16* __restrict__ q1, const bf16* __restrict__ q2,
                             const bf16* __restrict__ kbase, const bf16* __restrict__ vbase,
                             const float* __restrict__ lbuf, float* __restrict__ acc_out) {
    __shared__ __align__(16) bf16 Ka[8 * 32 * 72];   // [h][kv32][feat64 pad72]
    __shared__ __align__(16) bf16 Vt[128 * 40];      // [c][kv32 pad40] (kv-swizzled)
    __shared__ float invls[8 * 128];
    int qb = blockIdx.x, kvs = blockIdx.y, s = blockIdx.z;
    const bf16* Q  = s ? q2 : q1;
    const bf16* Kp = kbase + (size_t)s * KQ * DFEAT;
    const bf16* Vp = vbase + (size_t)s * KQ;
    int t = threadIdx.x, lane = t & 63, wid = t >> 6;
    int quad = lane >> 4, l15 = lane & 15;
    int qbase = qb * 128 + wid * 32;

    for (int i = t; i < 1024; i += 256) {
        int h = i >> 7, qq = i & 127;
        invls[i] = 1.0f / (8.0f * lbuf[(((size_t)s * NHEAD + h) << 12) + qb * 128 + qq]);
    }

    // Q fragments for all 8 heads (persist in registers)
    bf16x8 qf[8][2][2];
    #pragma unroll
    for (int h = 0; h < 8; h++)
        #pragma unroll
        for (int mt = 0; mt < 2; mt++)
            #pragma unroll
            for (int kc = 0; kc < 2; kc++)
                qf[h][mt][kc] = *(const bf16x8*)(Q + (size_t)(qbase + mt*16 + l15) * DFEAT + h*64 + kc*32 + quad*8);

    f32x4 O[2][8] = {};

    // staging maps
    int r8 = t >> 3, c8 = t & 7;   // K: per round j (=head), 8 thr/row
    int vr = t >> 1, vs = t & 1;   // V: 2 thr/row
    const bf16* kgs = Kp + (size_t)(kvs * 1024 + r8) * DFEAT + c8 * 8;
    const bf16* vgs = Vp + (size_t)vr * (2 * KQ) + kvs * 1024 + vs * 16;
    bf16* kws = &Ka[r8 * 72 + c8 * 8];
    bf16* vws = &Vt[vr * 40 + vs * 16];

    uint4 krg[8], vrg[2];
    #pragma unroll
    for (int j = 0; j < 8; j++) krg[j] = *(const uint4*)(kgs + j * 64);
    vrg[0] = *(const uint4*)vgs; vrg[1] = *(const uint4*)(vgs + 8);

    for (int it = 0; it < 32; it++) {
        #pragma unroll
        for (int j = 0; j < 8; j++) *(uint4*)(kws + j * 2304) = krg[j];
        *(uint4*)vws = vrg[0]; *(uint4*)(vws + 8) = vrg[1];
        __syncthreads();

        f32x4 Pb[2][2] = {};
        #pragma unroll
        for (int h = 0; h < 8; h++) {
            float iv0 = invls[h * 128 + wid * 32 + l15];
            float iv1 = invls[h * 128 + wid * 32 + 16 + l15];
            #pragma unroll
            for (int nt = 0; nt < 2; nt++) {
                bf16x8 ka = *(const bf16x8*)&Ka[h * 2304 + (nt*16 + l15) * 72 + quad * 8];
                bf16x8 kb = *(const bf16x8*)&Ka[h * 2304 + (nt*16 + l15) * 72 + 32 + quad * 8];
                #pragma unroll
                for (int mt = 0; mt < 2; mt++) {
                    f32x4 a = {};
                    a = MFMA16(ka, qf[h][mt][0], a);
                    a = MFMA16(kb, qf[h][mt][1], a);
                    float iv = mt ? iv1 : iv0;
                    #pragma unroll
                    for (int r = 0; r < 4; r++) Pb[mt][nt][r] += exp2f(a[r]) * iv;
                }
            }
        }
        // next-iter staged loads (in flight during PV + barrier)
        bool more = (it + 1 < 32);
        if (more) {
            size_t nxt = (size_t)(it + 1) * 32 * DFEAT;
            #pragma unroll
            for (int j = 0; j < 8; j++) krg[j] = *(const uint4*)(kgs + j * 64 + nxt);
            vrg[0] = *(const uint4*)(vgs + (it + 1) * 32);
            vrg[1] = *(const uint4*)(vgs + (it + 1) * 32 + 8);
        }
        // pack Pbar -> PV A-frags (identity mapping)
        bf16x8 P[2];
        #pragma unroll
        for (int mt = 0; mt < 2; mt++)
            #pragma unroll
            for (int nt = 0; nt < 2; nt++)
                #pragma unroll
                for (int r = 0; r < 4; r++)
                    P[mt][nt * 4 + r] = (bf16)Pb[mt][nt][r];
        #pragma unroll
        for (int ct = 0; ct < 8; ct++) {
            bf16x8 vb = *(const bf16x8*)&Vt[(ct*16 + l15) * 40 + quad * 8];
            #pragma unroll
            for (int mt = 0; mt < 2; mt++)
                O[mt][ct] = MFMA16(P[mt], vb, O[mt][ct]);
        }
        __syncthreads();
    }

    #pragma unroll
    for (int mt = 0; mt < 2; mt++)
        #pragma unroll
        for (int r = 0; r < 4; r++) {
            int row = qbase + mt*16 + quad*4 + r;
            #pragma unroll
            for (int ct = 0; ct < 8; ct++)
                atomicAdd(&acc_out[((size_t)s * N_Q + row) * NLAB + ct*16 + l15], O[mt][ct][r]);
        }
}

// ---------------- bias + cast ----------------
__global__ void bias_kernel(const float* __restrict__ acc, const void* __restrict__ bo,
                            void* __restrict__ out, const int* __restrict__ modep) {
    int f32m = *modep;
    int idx = blockIdx.x * 256 + threadIdx.x;
    float v = acc[idx] + loads(bo, idx & (NLAB - 1), f32m);
    if (f32m) ((float*)out)[idx] = v;
    else      ((bf16*)out)[idx] = (bf16)v;
}

extern "C" void kernel_launch(void* const* d_in, const int* in_sizes, int n_in,
                              void* d_out, int out_size, void* d_ws, size_t ws_size,
                              hipStream_t stream) {
    const void* anchor   = d_in[0];
    const void* positive = d_in[1];
    const void* lbfeat   = d_in[2];
    const void* lboh     = d_in[3];
    const void* ulb1     = d_in[5];
    const void* ulb2     = d_in[6];
    const void* fq1i     = d_in[7];
    const void* fq2i     = d_in[8];
    const void* lq1i     = d_in[9];
    const void* lq2i     = d_in[10];
    const void* Wq       = d_in[11];
    const void* Wk       = d_in[12];
    const void* Wo       = d_in[13];
    const void* bo       = d_in[14];

    char* ws = (char*)d_ws;
    int*  counts = (int*)(ws + OFF_COUNTS);
    int*  modep  = (int*)(ws + OFF_MODE);
    int*  flags  = (int*)(ws + OFF_FLAGS);
    int*  sel    = (int*)(ws + OFF_SEL);
    bf16* fq1  = (bf16*)(ws + OFF_FQ1);
    bf16* fq2  = (bf16*)(ws + OFF_FQ2);
    bf16* lq1  = (bf16*)(ws + OFF_LQ1);
    bf16* lq2  = (bf16*)(ws + OFF_LQ2);
    bf16* q1   = (bf16*)(ws + OFF_Q1);
    bf16* q2   = (bf16*)(ws + OFF_Q2);
    bf16* k1   = (bf16*)(ws + OFF_K1);
    bf16* wqT  = (bf16*)(ws + OFF_WQT);
    bf16* wkT  = (bf16*)(ws + OFF_WKT);
    bf16* woT  = (bf16*)(ws + OFF_WOT);
    bf16* vwt  = (bf16*)(ws + OFF_VWT);
    float* accb = (float*)(ws + OFF_ACC);
    float* lbuf = (float*)(ws + OFF_L);

    // zero O accumulator (4MB) + l buffer (256KB) in one contiguous memset
    hipMemsetAsync(accb, 0, (size_t)2 * N_Q * NLAB * sizeof(float)
                          + (size_t)2 * NHEAD * N_Q * sizeof(float), stream);

    detect_kernel<<<1, 256, 0, stream>>>(anchor, modep);
    flag_kernel<<<dim3(N_Q, 2), 64, 0, stream>>>(ulb1, ulb2, flags, modep);
    scan_kernel<<<2, 1024, 0, stream>>>(flags, sel, counts);
    buildq_kernel<<<dim3(KQ, 2), 128, 0, stream>>>(anchor, positive, lbfeat, lboh, ulb1, ulb2,
                                                   fq1i, fq2i, lq1i, lq2i, sel, counts,
                                                   fq1, fq2, lq1, lq2, modep);
    transpose_kernel<<<dim3(16, 16, 3), 256, 0, stream>>>(Wq, Wk, Wo, wqT, wkT, woT, modep);

    // q = (x @ Wq) * dh^-0.5 * log2(e)  — both streams in one launch (z)
    const float qalpha = 0.125f * 1.44269504088896f;
    gemm_nt<<<dim3(32, 4, 2), 256, 0, stream>>>(anchor, positive, wqT, q1, q2,
                                                4096, 512, 512, qalpha, modep, 1, 0);
    // k = [fq1;fq2] @ Wk  (merged, M=16384)
    gemm_nt<<<dim3(128, 4, 1), 256, 0, stream>>>(fq1, nullptr, wkT, k1, nullptr,
                                                 16384, 512, 512, 1.0f, modep, 0, 0);
    // VW^T = Wo^T @ lq^T, merged N=16384, kv-swizzled columns
    gemm_nt<<<dim3(1, 128, 1), 256, 0, stream>>>(woT, nullptr, lq1, vwt, nullptr,
                                                 128, 16384, 128, 1.0f, modep, 0, 1);

    pass1_kernel<<<dim3(128, NHEAD, 2), 128, 0, stream>>>(q1, q2, k1, lbuf);
    pass2_kernel<<<dim3(32, 8, 2), 256, 0, stream>>>(q1, q2, k1, vwt, lbuf, accb);
    bias_kernel<<<(2 * N_Q * NLAB) / 256, 256, 0, stream>>>(accb, bo, d_out, modep);
}

// Round 6
// 633.596 us; speedup vs baseline: 1.3991x; 1.3991x over previous
//
#include <hip/hip_runtime.h>

typedef __bf16 bf16;
typedef __bf16 bf16x8 __attribute__((ext_vector_type(8)));
typedef float f32x4 __attribute__((ext_vector_type(4)));

#define MFMA16(a,b,c) __builtin_amdgcn_mfma_f32_16x16x32_bf16(a,b,c,0,0,0)

#define N_Q   4096
#define DFEAT 512
#define KQ    8192
#define NLAB  128
#define NHEAD 8

// ---------------- workspace layout (bytes) ----------------
#define MBv (1024ull*1024ull)
#define OFF_COUNTS 0ull
#define OFF_MODE   512ull
#define OFF_FLAGS  1024ull
#define OFF_SEL    (64ull*1024ull)
#define OFF_FQ1    (1ull*MBv)   // 8192x512 bf16 = 8MB (dead after k-gemm; reused as PART)
#define OFF_FQ2    (9ull*MBv)
#define OFF_LQ1    (17ull*MBv)
#define OFF_LQ2    (19ull*MBv)
#define OFF_Q1     (21ull*MBv)
#define OFF_Q2     (25ull*MBv)
#define OFF_K1     (29ull*MBv)  // 16384x512 bf16 (both streams)
#define OFF_WQT    (45ull*MBv)
#define OFF_WKT    (46ull*MBv)
#define OFF_WOT    (47ull*MBv)
#define OFF_VWT    (48ull*MBv)  // 128x16384 bf16 (VW^T, kv-swizzled)
#define OFF_LP     (52ull*MBv)  // lpart: 8x8x4096 f32 = 1MB
#define OFF_PART   OFF_FQ1      // 2hg x 8x x 32qb x 128q x 128c bf16 = 16MB

// ---------------- dtype-agnostic loads ----------------
__device__ __forceinline__ float loads(const void* p, size_t i, int f32m) {
    return f32m ? ((const float*)p)[i] : (float)((const bf16*)p)[i];
}
__device__ __forceinline__ bf16x8 load8(const void* p, size_t i, int f32m) {
    bf16x8 r;
    if (f32m) {
        const float4* q = (const float4*)((const float*)p + i);
        float4 f0 = q[0], f1 = q[1];
        r[0] = (bf16)f0.x; r[1] = (bf16)f0.y; r[2] = (bf16)f0.z; r[3] = (bf16)f0.w;
        r[4] = (bf16)f1.x; r[5] = (bf16)f1.y; r[6] = (bf16)f1.z; r[7] = (bf16)f1.w;
    } else {
        r = *(const bf16x8*)((const bf16*)p + i);
    }
    return r;
}

// ---------------- dtype detector ----------------
__global__ void detect_kernel(const void* probe, int* mode) {
    const unsigned short* u = (const unsigned short*)probe;
    int t = threadIdx.x;
    int bad = 0;
    for (int i = t; i < 2048; i += 256) {
        unsigned short v = u[2 * i];
        int e = (v >> 7) & 0xFF;
        if (e > 140 || (e < 60 && e != 0)) bad++;
    }
    __shared__ int sb[256];
    sb[t] = bad;
    __syncthreads();
    for (int off = 128; off; off >>= 1) {
        if (t < off) sb[t] += sb[t + off];
        __syncthreads();
    }
    if (t == 0) mode[0] = (sb[0] > 200) ? 1 : 0;
}

// ---------------- flag: row-max > 0.95 ----------------
__global__ void flag_kernel(const void* __restrict__ ulb1, const void* __restrict__ ulb2,
                            int* __restrict__ flags, const int* __restrict__ modep) {
    int f32m = *modep;
    int row = blockIdx.x, s = blockIdx.y, t = threadIdx.x; // 64 threads
    const void* p = s ? ulb2 : ulb1;
    size_t base = (size_t)row * NLAB;
    float m = fmaxf(loads(p, base + t, f32m), loads(p, base + t + 64, f32m));
    #pragma unroll
    for (int off = 32; off; off >>= 1) m = fmaxf(m, __shfl_xor(m, off));
    if (t == 0) flags[s * N_Q + row] = (m > 0.95f) ? 1 : 0;
}

// ---------------- scan: stable compaction ----------------
__global__ void scan_kernel(const int* __restrict__ flags, int* __restrict__ sel,
                            int* __restrict__ counts) {
    int s = blockIdx.x, t = threadIdx.x; // 1024 threads
    const int* f = flags + s * N_Q;
    int* selp = sel + s * N_Q;
    __shared__ int ls[1024];
    int f0 = f[t*4], f1 = f[t*4+1], f2 = f[t*4+2], f3 = f[t*4+3];
    int local = f0 + f1 + f2 + f3;
    ls[t] = local;
    __syncthreads();
    for (int off = 1; off < 1024; off <<= 1) {
        int v = (t >= off) ? ls[t - off] : 0;
        __syncthreads();
        ls[t] += v;
        __syncthreads();
    }
    int pos = ls[t] - local;
    if (f0) selp[pos++] = t*4;
    if (f1) selp[pos++] = t*4+1;
    if (f2) selp[pos++] = t*4+2;
    if (f3) selp[pos++] = t*4+3;
    if (t == 1023) counts[s] = ls[1023];
}

// ---------------- build queues ----------------
__global__ void buildq_kernel(const void* __restrict__ anchor, const void* __restrict__ positive,
                              const void* __restrict__ lbfeat, const void* __restrict__ lboh,
                              const void* __restrict__ ulb1, const void* __restrict__ ulb2,
                              const void* __restrict__ fq1i, const void* __restrict__ fq2i,
                              const void* __restrict__ lq1i, const void* __restrict__ lq2i,
                              const int* __restrict__ sel, const int* __restrict__ counts,
                              bf16* __restrict__ fq1o, bf16* __restrict__ fq2o,
                              bf16* __restrict__ lq1o, bf16* __restrict__ lq2o,
                              const int* __restrict__ modep) {
    int f32m = *modep;
    int i = blockIdx.x, s = blockIdx.y, t = threadIdx.x; // 128 threads
    int C = counts[s];
    const void *fb, *lb;
    size_t frow, lrow;
    if (i < C) {
        int r = sel[s * N_Q + i];
        fb = s ? positive : anchor; frow = r;
        lb = s ? ulb2 : ulb1;       lrow = r;
    } else if (i < C + 512) {
        int r = i - C + s * 512;
        fb = lbfeat; frow = r;
        lb = lboh;   lrow = r;
    } else {
        int r = i - C - 512;
        fb = s ? fq2i : fq1i; frow = r;
        lb = s ? lq2i : lq1i; lrow = r;
    }
    bf16* fd = (s ? fq2o : fq1o) + (size_t)i * DFEAT;
    bf16* ld = (s ? lq2o : lq1o) + (size_t)i * NLAB;
    if (t < 64)      *(bf16x8*)&fd[t * 8]        = load8(fb, frow * DFEAT + (size_t)t * 8, f32m);
    else if (t < 80) *(bf16x8*)&ld[(t - 64) * 8] = load8(lb, lrow * NLAB + (size_t)(t - 64) * 8, f32m);
}

// ---------------- fused transposes (z: 0=Wq, 1=Wk, 2=Wo) ----------------
__global__ void transpose_kernel(const void* __restrict__ Wq, const void* __restrict__ Wk,
                                 const void* __restrict__ Wo,
                                 bf16* __restrict__ Tq, bf16* __restrict__ Tk, bf16* __restrict__ To,
                                 const int* __restrict__ modep) {
    int z = blockIdx.z;
    const void* W = (z == 0) ? Wq : (z == 1) ? Wk : Wo;
    bf16* T = (z == 0) ? Tq : (z == 1) ? Tk : To;
    int n = (z == 2) ? 128 : 512;
    if (z == 2 && (blockIdx.x >= 4 || blockIdx.y >= 4)) return;
    int f32m = *modep;
    __shared__ bf16 tile[32][33];
    int bx = blockIdx.x * 32, by = blockIdx.y * 32;
    int tx = threadIdx.x & 31, ty = threadIdx.x >> 5;
    for (int r = ty; r < 32; r += 8) tile[r][tx] = (bf16)loads(W, (size_t)(by + r) * n + bx + tx, f32m);
    __syncthreads();
    for (int r = ty; r < 32; r += 8) T[(size_t)(bx + r) * n + by + tx] = tile[tx][r];
}

// ---------------- NT GEMM: C = alpha * A @ Bt^T; optional kv-swizzle; optional batch-2 ----------------
__launch_bounds__(256, 2)
__global__ void gemm_nt(const void* __restrict__ A, const void* __restrict__ A2,
                        const bf16* __restrict__ B,
                        bf16* __restrict__ C, bf16* __restrict__ C2,
                        int M, int N, int Kd, float alpha,
                        const int* __restrict__ modep, int a_raw, int swz) {
    int f32m = a_raw ? *modep : 0;
    if (blockIdx.z) { A = A2; C = C2; }
    __shared__ __align__(16) bf16 As[128 * 72];
    __shared__ __align__(16) bf16 Bs[128 * 72];
    int m0 = blockIdx.x * 128, n0 = blockIdx.y * 128;
    int t = threadIdx.x, lane = t & 63, wid = t >> 6;
    int quad = lane >> 4, l15 = lane & 15;
    int wrow = (wid >> 1) * 64, wcol = (wid & 1) * 64;
    int srow = t >> 1, sseg = t & 1;
    f32x4 acc[4][4] = {};
    for (int k0 = 0; k0 < Kd; k0 += 32) {
        __syncthreads();
        bf16x8 a0 = load8(A, (size_t)(m0 + srow) * Kd + k0 + sseg * 8, f32m);
        bf16x8 a1 = load8(A, (size_t)(m0 + srow) * Kd + k0 + (sseg + 2) * 8, f32m);
        const uint4* gb = (const uint4*)(B + (size_t)(n0 + srow) * Kd + k0);
        uint4 b0 = gb[sseg], b1 = gb[sseg + 2];
        *(bf16x8*)&As[srow * 72 + sseg * 8]       = a0;
        *(bf16x8*)&As[srow * 72 + (sseg + 2) * 8] = a1;
        *(uint4*)&Bs[srow * 72 + sseg * 8]        = b0;
        *(uint4*)&Bs[srow * 72 + (sseg + 2) * 8]  = b1;
        __syncthreads();
        bf16x8 af[4], bfr[4];
        #pragma unroll
        for (int mt = 0; mt < 4; mt++) af[mt]  = *(const bf16x8*)&As[(wrow + mt*16 + l15) * 72 + quad * 8];
        #pragma unroll
        for (int nt = 0; nt < 4; nt++) bfr[nt] = *(const bf16x8*)&Bs[(wcol + nt*16 + l15) * 72 + quad * 8];
        #pragma unroll
        for (int mt = 0; mt < 4; mt++)
            #pragma unroll
            for (int nt = 0; nt < 4; nt++)
                acc[mt][nt] = MFMA16(af[mt], bfr[nt], acc[mt][nt]);
    }
    #pragma unroll
    for (int mt = 0; mt < 4; mt++)
        #pragma unroll
        for (int nt = 0; nt < 4; nt++)
            #pragma unroll
            for (int r = 0; r < 4; r++) {
                int row = m0 + wrow + mt*16 + quad*4 + r;
                int col = n0 + wcol + nt*16 + l15;
                if (swz) col = (col & ~31) | (((col & 12) << 1) | ((col & 16) >> 2) | (col & 3));
                C[(size_t)row * N + col] = (bf16)(acc[mt][nt][r] * alpha);
            }
}

// ---------------- pass 1: partial softmax denominators (no atomics, h pinned to XCD) ----------------
__launch_bounds__(128, 4)
__global__ void pass1_kernel(const bf16* __restrict__ q1, const bf16* __restrict__ q2,
                             const bf16* __restrict__ kbase, float* __restrict__ lpart) {
    __shared__ __align__(16) bf16 Kt[64 * 72];
    int h = blockIdx.x;                       // grid.x=8 -> XCD = h (round-robin)
    int qb = blockIdx.y >> 2, kvs = blockIdx.y & 3, s = blockIdx.z;
    const bf16* Q  = s ? q2 : q1;
    const bf16* Kp = kbase + (size_t)s * KQ * DFEAT + h * 64;
    int t = threadIdx.x, lane = t & 63, wid = t >> 6;  // 2 waves
    int quad = lane >> 4, l15 = lane & 15;
    int qbase = qb * 128 + wid * 64;

    bf16x8 qf[4][2];
    #pragma unroll
    for (int mt = 0; mt < 4; mt++)
        #pragma unroll
        for (int kc = 0; kc < 2; kc++)
            qf[mt][kc] = *(const bf16x8*)(Q + (size_t)(qbase + mt*16 + l15) * DFEAT + h*64 + kc*32 + quad*8);

    int kr = t >> 1, ks = t & 1;
    const bf16* kg = Kp + (size_t)(kvs * 2048 + kr) * DFEAT + ks * 32;
    bf16* kw = &Kt[kr * 72 + ks * 32];
    uint4 n0 = *(const uint4*)kg, n1 = *(const uint4*)(kg + 8);
    uint4 n2 = *(const uint4*)(kg + 16), n3 = *(const uint4*)(kg + 24);
    *(uint4*)kw = n0; *(uint4*)(kw + 8) = n1;
    *(uint4*)(kw + 16) = n2; *(uint4*)(kw + 24) = n3;
    __syncthreads();

    float lsum[4] = {0.f, 0.f, 0.f, 0.f};
    for (int it = 0; it < 32; it++) {
        bool more = (it + 1 < 32);
        if (more) {
            const bf16* kn = kg + (size_t)(it + 1) * 64 * DFEAT;
            n0 = *(const uint4*)kn; n1 = *(const uint4*)(kn + 8);
            n2 = *(const uint4*)(kn + 16); n3 = *(const uint4*)(kn + 24);
        }
        #pragma unroll
        for (int nt = 0; nt < 4; nt++) {
            bf16x8 k0 = *(const bf16x8*)&Kt[(nt*16 + l15) * 72 + quad * 8];
            bf16x8 k1 = *(const bf16x8*)&Kt[(nt*16 + l15) * 72 + 32 + quad * 8];
            #pragma unroll
            for (int mt = 0; mt < 4; mt++) {
                f32x4 a = {};
                a = MFMA16(k0, qf[mt][0], a);
                a = MFMA16(k1, qf[mt][1], a);
                lsum[mt] += exp2f(a[0]) + exp2f(a[1]) + exp2f(a[2]) + exp2f(a[3]);
            }
        }
        __syncthreads();
        if (more) {
            *(uint4*)kw = n0; *(uint4*)(kw + 8) = n1;
            *(uint4*)(kw + 16) = n2; *(uint4*)(kw + 24) = n3;
        }
        __syncthreads();
    }
    #pragma unroll
    for (int mt = 0; mt < 4; mt++) {
        lsum[mt] += __shfl_xor(lsum[mt], 16);
        lsum[mt] += __shfl_xor(lsum[mt], 32);
    }
    if (quad == 0) {
        #pragma unroll
        for (int mt = 0; mt < 4; mt++)
            lpart[(((size_t)(kvs + 4*s)) * NHEAD + h) * N_Q + qbase + mt*16 + l15] = lsum[mt];
    }
}

// ---------------- pass 2: head-group-fused Pbar + single PV; bf16 partials, no atomics ----------------
__launch_bounds__(256, 2)
__global__ void pass2_kernel(const bf16* __restrict__ q1, const bf16* __restrict__ q2,
                             const bf16* __restrict__ kbase, const bf16* __restrict__ vbase,
                             const float* __restrict__ lpart, bf16* __restrict__ part) {
    __shared__ __align__(16) bf16 Ka[4 * 32 * 72];   // [j][kv32][feat64 pad72] = 18KB
    __shared__ __align__(16) bf16 Vt[128 * 40];      // [c][kv32 pad40] = 10KB
    int x = blockIdx.x;                // kvs + 4*s; grid.x=8 -> XCD = x
    int kvs = x & 3, s = x >> 2;
    int qb = blockIdx.y, hg = blockIdx.z;
    const bf16* Q  = s ? q2 : q1;
    const bf16* Kp = kbase + (size_t)s * KQ * DFEAT;
    const bf16* Vp = vbase + (size_t)s * KQ;
    int t = threadIdx.x, lane = t & 63, wid = t >> 6;
    int quad = lane >> 4, l15 = lane & 15;

    // per-lane inverse denominators (lane's two q rows) for this head group
    float iv[4][2];
    #pragma unroll
    for (int j = 0; j < 4; j++)
        #pragma unroll
        for (int mt = 0; mt < 2; mt++) {
            int q = qb * 128 + wid * 32 + mt * 16 + l15;
            float sum = 0.f;
            #pragma unroll
            for (int k = 0; k < 4; k++)
                sum += lpart[(((size_t)(k + 4*s)) * NHEAD + hg*4 + j) * N_Q + q];
            iv[j][mt] = 1.0f / (8.0f * sum);
        }

    // Q B-frags for 4 heads x 2 q-tiles (registers)
    bf16x8 qf[4][2][2];
    #pragma unroll
    for (int j = 0; j < 4; j++)
        #pragma unroll
        for (int mt = 0; mt < 2; mt++)
            #pragma unroll
            for (int ch = 0; ch < 2; ch++)
                qf[j][mt][ch] = *(const bf16x8*)(Q + (size_t)(qb*128 + wid*32 + mt*16 + l15) * DFEAT
                                                  + (hg*4 + j)*64 + ch*32 + quad*8);

    f32x4 O[2][8] = {};

    // staging maps (bank-balanced)
    int r8 = t >> 3, c8 = t & 7;       // K: 32 rows x 8 granules
    int vr = t >> 1, vs = t & 1;       // V: 128 rows x 2 halves
    const bf16* kgs = Kp + (size_t)(kvs * 2048 + r8) * DFEAT + hg * 256 + c8 * 8;
    const bf16* vgs = Vp + (size_t)vr * (2 * KQ) + kvs * 2048 + vs * 16;
    bf16* kws = &Ka[r8 * 72 + c8 * 8];
    bf16* vws = &Vt[vr * 40 + vs * 16];

    uint4 krg[4], vrg[2];
    #pragma unroll
    for (int j = 0; j < 4; j++) krg[j] = *(const uint4*)(kgs + j * 64);
    vrg[0] = *(const uint4*)vgs; vrg[1] = *(const uint4*)(vgs + 8);

    for (int it = 0; it < 64; it++) {
        #pragma unroll
        for (int j = 0; j < 4; j++) *(uint4*)(kws + j * 2304) = krg[j];
        *(uint4*)vws = vrg[0]; *(uint4*)(vws + 8) = vrg[1];
        __syncthreads();
        bool more = (it + 1 < 64);
        if (more) {
            size_t nk = (size_t)(it + 1) * 32 * DFEAT;
            #pragma unroll
            for (int j = 0; j < 4; j++) krg[j] = *(const uint4*)(kgs + j * 64 + nk);
            vrg[0] = *(const uint4*)(vgs + (it + 1) * 32);
            vrg[1] = *(const uint4*)(vgs + (it + 1) * 32 + 8);
        }
        f32x4 Pb[2][2] = {};
        #pragma unroll
        for (int j = 0; j < 4; j++) {
            #pragma unroll
            for (int nt = 0; nt < 2; nt++) {
                bf16x8 ka = *(const bf16x8*)&Ka[j * 2304 + (nt*16 + l15) * 72 + quad * 8];
                bf16x8 kb = *(const bf16x8*)&Ka[j * 2304 + (nt*16 + l15) * 72 + 32 + quad * 8];
                #pragma unroll
                for (int mt = 0; mt < 2; mt++) {
                    f32x4 a = {};
                    a = MFMA16(ka, qf[j][mt][0], a);
                    a = MFMA16(kb, qf[j][mt][1], a);
                    float ivv = iv[j][mt];
                    #pragma unroll
                    for (int r = 0; r < 4; r++) Pb[mt][nt][r] += exp2f(a[r]) * ivv;
                }
            }
        }
        bf16x8 P[2];
        #pragma unroll
        for (int mt = 0; mt < 2; mt++)
            #pragma unroll
            for (int nt = 0; nt < 2; nt++)
                #pragma unroll
                for (int r = 0; r < 4; r++)
                    P[mt][nt * 4 + r] = (bf16)Pb[mt][nt][r];
        #pragma unroll
        for (int ct = 0; ct < 8; ct++) {
            bf16x8 vb = *(const bf16x8*)&Vt[(ct*16 + l15) * 40 + quad * 8];
            #pragma unroll
            for (int mt = 0; mt < 2; mt++)
                O[mt][ct] = MFMA16(P[mt], vb, O[mt][ct]);
        }
        __syncthreads();
    }

    // store bf16 partial O tile: part[hg][x][qb][128q][128c]
    size_t pbase = (((size_t)(hg * 8 + x) * 32 + qb) * 128) * 128;
    #pragma unroll
    for (int mt = 0; mt < 2; mt++)
        #pragma unroll
        for (int r = 0; r < 4; r++) {
            int ql = wid*32 + mt*16 + quad*4 + r;
            #pragma unroll
            for (int ct = 0; ct < 8; ct++)
                part[pbase + (size_t)ql * 128 + ct*16 + l15] = (bf16)O[mt][ct][r];
        }
}

// ---------------- reduce partials + bias + cast ----------------
__global__ void reduce_kernel(const bf16* __restrict__ part, const void* __restrict__ bo,
                              void* __restrict__ out, const int* __restrict__ modep) {
    int f32m = *modep;
    int idx = blockIdx.x * 256 + threadIdx.x;    // 2*4096*128
    int c = idx & 127;
    int q = (idx >> 7) & 4095;
    int s = idx >> 19;
    int qb = q >> 7, ql = q & 127;
    float v = loads(bo, c, f32m);
    #pragma unroll
    for (int hg = 0; hg < 2; hg++)
        #pragma unroll
        for (int k = 0; k < 4; k++) {
            int x = k + 4 * s;
            v += (float)part[(((size_t)(hg * 8 + x) * 32 + qb) * 128 + ql) * 128 + c];
        }
    if (f32m) ((float*)out)[idx] = v;
    else      ((bf16*)out)[idx] = (bf16)v;
}

extern "C" void kernel_launch(void* const* d_in, const int* in_sizes, int n_in,
                              void* d_out, int out_size, void* d_ws, size_t ws_size,
                              hipStream_t stream) {
    const void* anchor   = d_in[0];
    const void* positive = d_in[1];
    const void* lbfeat   = d_in[2];
    const void* lboh     = d_in[3];
    const void* ulb1     = d_in[5];
    const void* ulb2     = d_in[6];
    const void* fq1i     = d_in[7];
    const void* fq2i     = d_in[8];
    const void* lq1i     = d_in[9];
    const void* lq2i     = d_in[10];
    const void* Wq       = d_in[11];
    const void* Wk       = d_in[12];
    const void* Wo       = d_in[13];
    const void* bo       = d_in[14];

    char* ws = (char*)d_ws;
    int*  counts = (int*)(ws + OFF_COUNTS);
    int*  modep  = (int*)(ws + OFF_MODE);
    int*  flags  = (int*)(ws + OFF_FLAGS);
    int*  sel    = (int*)(ws + OFF_SEL);
    bf16* fq1  = (bf16*)(ws + OFF_FQ1);
    bf16* fq2  = (bf16*)(ws + OFF_FQ2);
    bf16* lq1  = (bf16*)(ws + OFF_LQ1);
    bf16* lq2  = (bf16*)(ws + OFF_LQ2);
    bf16* q1   = (bf16*)(ws + OFF_Q1);
    bf16* q2   = (bf16*)(ws + OFF_Q2);
    bf16* k1   = (bf16*)(ws + OFF_K1);
    bf16* wqT  = (bf16*)(ws + OFF_WQT);
    bf16* wkT  = (bf16*)(ws + OFF_WKT);
    bf16* woT  = (bf16*)(ws + OFF_WOT);
    bf16* vwt  = (bf16*)(ws + OFF_VWT);
    float* lpart = (float*)(ws + OFF_LP);
    bf16* part   = (bf16*)(ws + OFF_PART);

    detect_kernel<<<1, 256, 0, stream>>>(anchor, modep);
    flag_kernel<<<dim3(N_Q, 2), 64, 0, stream>>>(ulb1, ulb2, flags, modep);
    scan_kernel<<<2, 1024, 0, stream>>>(flags, sel, counts);
    buildq_kernel<<<dim3(KQ, 2), 128, 0, stream>>>(anchor, positive, lbfeat, lboh, ulb1, ulb2,
                                                   fq1i, fq2i, lq1i, lq2i, sel, counts,
                                                   fq1, fq2, lq1, lq2, modep);
    transpose_kernel<<<dim3(16, 16, 3), 256, 0, stream>>>(Wq, Wk, Wo, wqT, wkT, woT, modep);

    // q = (x @ Wq) * dh^-0.5 * log2(e)  — both streams in one launch (z)
    const float qalpha = 0.125f * 1.44269504088896f;
    gemm_nt<<<dim3(32, 4, 2), 256, 0, stream>>>(anchor, positive, wqT, q1, q2,
                                                4096, 512, 512, qalpha, modep, 1, 0);
    // k = [fq1;fq2] @ Wk  (merged, M=16384)
    gemm_nt<<<dim3(128, 4, 1), 256, 0, stream>>>(fq1, nullptr, wkT, k1, nullptr,
                                                 16384, 512, 512, 1.0f, modep, 0, 0);
    // VW^T = Wo^T @ lq^T, merged N=16384, kv-swizzled columns
    gemm_nt<<<dim3(1, 128, 1), 256, 0, stream>>>(woT, nullptr, lq1, vwt, nullptr,
                                                 128, 16384, 128, 1.0f, modep, 0, 1);

    pass1_kernel<<<dim3(8, 128, 2), 128, 0, stream>>>(q1, q2, k1, lpart);
    pass2_kernel<<<dim3(8, 32, 2), 256, 0, stream>>>(q1, q2, k1, vwt, lpart, part);
    reduce_kernel<<<(2 * N_Q * NLAB) / 256, 256, 0, stream>>>(part, bo, d_out, modep);
}

// Round 7
// 599.345 us; speedup vs baseline: 1.4791x; 1.0571x over previous
//
#include <hip/hip_runtime.h>

typedef __bf16 bf16;
typedef __bf16 bf16x8 __attribute__((ext_vector_type(8)));
typedef float f32x4 __attribute__((ext_vector_type(4)));

#define MFMA16(a,b,c) __builtin_amdgcn_mfma_f32_16x16x32_bf16(a,b,c,0,0,0)

#define N_Q   4096
#define DFEAT 512
#define KQ    8192
#define NLAB  128
#define NHEAD 8

// ---------------- workspace layout (bytes) ----------------
#define MBv (1024ull*1024ull)
#define OFF_COUNTS 0ull
#define OFF_MODE   512ull
#define OFF_FLAGS  1024ull
#define OFF_SEL    (64ull*1024ull)
#define OFF_FQ1    (1ull*MBv)
#define OFF_FQ2    (9ull*MBv)
#define OFF_LQ1    (17ull*MBv)
#define OFF_LQ2    (19ull*MBv)
#define OFF_Q1     (21ull*MBv)
#define OFF_Q2     (25ull*MBv)
#define OFF_K1     (29ull*MBv)  // 16384x512 bf16 (both streams)
#define OFF_WQT    (45ull*MBv)
#define OFF_WKT    (46ull*MBv)
#define OFF_WOT    (47ull*MBv)
#define OFF_VWT    (48ull*MBv)  // 128x16384 bf16 (VW^T, kv-swizzled)
#define OFF_ACC    (52ull*MBv)  // 2x4096x128 f32 = 4MB

// ---------------- dtype-agnostic loads ----------------
__device__ __forceinline__ float loads(const void* p, size_t i, int f32m) {
    return f32m ? ((const float*)p)[i] : (float)((const bf16*)p)[i];
}
__device__ __forceinline__ bf16x8 load8(const void* p, size_t i, int f32m) {
    bf16x8 r;
    if (f32m) {
        const float4* q = (const float4*)((const float*)p + i);
        float4 f0 = q[0], f1 = q[1];
        r[0] = (bf16)f0.x; r[1] = (bf16)f0.y; r[2] = (bf16)f0.z; r[3] = (bf16)f0.w;
        r[4] = (bf16)f1.x; r[5] = (bf16)f1.y; r[6] = (bf16)f1.z; r[7] = (bf16)f1.w;
    } else {
        r = *(const bf16x8*)((const bf16*)p + i);
    }
    return r;
}

// ---------------- dtype detector ----------------
__global__ void detect_kernel(const void* probe, int* mode) {
    const unsigned short* u = (const unsigned short*)probe;
    int t = threadIdx.x;
    int bad = 0;
    for (int i = t; i < 2048; i += 256) {
        unsigned short v = u[2 * i];
        int e = (v >> 7) & 0xFF;
        if (e > 140 || (e < 60 && e != 0)) bad++;
    }
    __shared__ int sb[256];
    sb[t] = bad;
    __syncthreads();
    for (int off = 128; off; off >>= 1) {
        if (t < off) sb[t] += sb[t + off];
        __syncthreads();
    }
    if (t == 0) mode[0] = (sb[0] > 200) ? 1 : 0;
}

// ---------------- flag: row-max > 0.95 ----------------
__global__ void flag_kernel(const void* __restrict__ ulb1, const void* __restrict__ ulb2,
                            int* __restrict__ flags, const int* __restrict__ modep) {
    int f32m = *modep;
    int row = blockIdx.x, s = blockIdx.y, t = threadIdx.x; // 64 threads
    const void* p = s ? ulb2 : ulb1;
    size_t base = (size_t)row * NLAB;
    float m = fmaxf(loads(p, base + t, f32m), loads(p, base + t + 64, f32m));
    #pragma unroll
    for (int off = 32; off; off >>= 1) m = fmaxf(m, __shfl_xor(m, off));
    if (t == 0) flags[s * N_Q + row] = (m > 0.95f) ? 1 : 0;
}

// ---------------- scan: stable compaction ----------------
__global__ void scan_kernel(const int* __restrict__ flags, int* __restrict__ sel,
                            int* __restrict__ counts) {
    int s = blockIdx.x, t = threadIdx.x; // 1024 threads
    const int* f = flags + s * N_Q;
    int* selp = sel + s * N_Q;
    __shared__ int ls[1024];
    int f0 = f[t*4], f1 = f[t*4+1], f2 = f[t*4+2], f3 = f[t*4+3];
    int local = f0 + f1 + f2 + f3;
    ls[t] = local;
    __syncthreads();
    for (int off = 1; off < 1024; off <<= 1) {
        int v = (t >= off) ? ls[t - off] : 0;
        __syncthreads();
        ls[t] += v;
        __syncthreads();
    }
    int pos = ls[t] - local;
    if (f0) selp[pos++] = t*4;
    if (f1) selp[pos++] = t*4+1;
    if (f2) selp[pos++] = t*4+2;
    if (f3) selp[pos++] = t*4+3;
    if (t == 1023) counts[s] = ls[1023];
}

// ---------------- build queues ----------------
__global__ void buildq_kernel(const void* __restrict__ anchor, const void* __restrict__ positive,
                              const void* __restrict__ lbfeat, const void* __restrict__ lboh,
                              const void* __restrict__ ulb1, const void* __restrict__ ulb2,
                              const void* __restrict__ fq1i, const void* __restrict__ fq2i,
                              const void* __restrict__ lq1i, const void* __restrict__ lq2i,
                              const int* __restrict__ sel, const int* __restrict__ counts,
                              bf16* __restrict__ fq1o, bf16* __restrict__ fq2o,
                              bf16* __restrict__ lq1o, bf16* __restrict__ lq2o,
                              const int* __restrict__ modep) {
    int f32m = *modep;
    int i = blockIdx.x, s = blockIdx.y, t = threadIdx.x; // 128 threads
    int C = counts[s];
    const void *fb, *lb;
    size_t frow, lrow;
    if (i < C) {
        int r = sel[s * N_Q + i];
        fb = s ? positive : anchor; frow = r;
        lb = s ? ulb2 : ulb1;       lrow = r;
    } else if (i < C + 512) {
        int r = i - C + s * 512;
        fb = lbfeat; frow = r;
        lb = lboh;   lrow = r;
    } else {
        int r = i - C - 512;
        fb = s ? fq2i : fq1i; frow = r;
        lb = s ? lq2i : lq1i; lrow = r;
    }
    bf16* fd = (s ? fq2o : fq1o) + (size_t)i * DFEAT;
    bf16* ld = (s ? lq2o : lq1o) + (size_t)i * NLAB;
    if (t < 64)      *(bf16x8*)&fd[t * 8]        = load8(fb, frow * DFEAT + (size_t)t * 8, f32m);
    else if (t < 80) *(bf16x8*)&ld[(t - 64) * 8] = load8(lb, lrow * NLAB + (size_t)(t - 64) * 8, f32m);
}

// ---------------- fused transposes (z: 0=Wq, 1=Wk, 2=Wo) ----------------
__global__ void transpose_kernel(const void* __restrict__ Wq, const void* __restrict__ Wk,
                                 const void* __restrict__ Wo,
                                 bf16* __restrict__ Tq, bf16* __restrict__ Tk, bf16* __restrict__ To,
                                 const int* __restrict__ modep) {
    int z = blockIdx.z;
    const void* W = (z == 0) ? Wq : (z == 1) ? Wk : Wo;
    bf16* T = (z == 0) ? Tq : (z == 1) ? Tk : To;
    int n = (z == 2) ? 128 : 512;
    if (z == 2 && (blockIdx.x >= 4 || blockIdx.y >= 4)) return;
    int f32m = *modep;
    __shared__ bf16 tile[32][33];
    int bx = blockIdx.x * 32, by = blockIdx.y * 32;
    int tx = threadIdx.x & 31, ty = threadIdx.x >> 5;
    for (int r = ty; r < 32; r += 8) tile[r][tx] = (bf16)loads(W, (size_t)(by + r) * n + bx + tx, f32m);
    __syncthreads();
    for (int r = ty; r < 32; r += 8) T[(size_t)(bx + r) * n + by + tx] = tile[tx][r];
}

// ---------------- NT GEMM: C = alpha * A @ Bt^T; optional kv-swizzle; optional batch-2 ----------------
__launch_bounds__(256, 2)
__global__ void gemm_nt(const void* __restrict__ A, const void* __restrict__ A2,
                        const bf16* __restrict__ B,
                        bf16* __restrict__ C, bf16* __restrict__ C2,
                        int M, int N, int Kd, float alpha,
                        const int* __restrict__ modep, int a_raw, int swz) {
    int f32m = a_raw ? *modep : 0;
    if (blockIdx.z) { A = A2; C = C2; }
    __shared__ __align__(16) bf16 As[128 * 72];
    __shared__ __align__(16) bf16 Bs[128 * 72];
    int m0 = blockIdx.x * 128, n0 = blockIdx.y * 128;
    int t = threadIdx.x, lane = t & 63, wid = t >> 6;
    int quad = lane >> 4, l15 = lane & 15;
    int wrow = (wid >> 1) * 64, wcol = (wid & 1) * 64;
    int srow = t >> 1, sseg = t & 1;
    f32x4 acc[4][4] = {};
    for (int k0 = 0; k0 < Kd; k0 += 32) {
        __syncthreads();
        bf16x8 a0 = load8(A, (size_t)(m0 + srow) * Kd + k0 + sseg * 8, f32m);
        bf16x8 a1 = load8(A, (size_t)(m0 + srow) * Kd + k0 + (sseg + 2) * 8, f32m);
        const uint4* gb = (const uint4*)(B + (size_t)(n0 + srow) * Kd + k0);
        uint4 b0 = gb[sseg], b1 = gb[sseg + 2];
        *(bf16x8*)&As[srow * 72 + sseg * 8]       = a0;
        *(bf16x8*)&As[srow * 72 + (sseg + 2) * 8] = a1;
        *(uint4*)&Bs[srow * 72 + sseg * 8]        = b0;
        *(uint4*)&Bs[srow * 72 + (sseg + 2) * 8]  = b1;
        __syncthreads();
        bf16x8 af[4], bfr[4];
        #pragma unroll
        for (int mt = 0; mt < 4; mt++) af[mt]  = *(const bf16x8*)&As[(wrow + mt*16 + l15) * 72 + quad * 8];
        #pragma unroll
        for (int nt = 0; nt < 4; nt++) bfr[nt] = *(const bf16x8*)&Bs[(wcol + nt*16 + l15) * 72 + quad * 8];
        #pragma unroll
        for (int mt = 0; mt < 4; mt++)
            #pragma unroll
            for (int nt = 0; nt < 4; nt++)
                acc[mt][nt] = MFMA16(af[mt], bfr[nt], acc[mt][nt]);
    }
    #pragma unroll
    for (int mt = 0; mt < 4; mt++)
        #pragma unroll
        for (int nt = 0; nt < 4; nt++)
            #pragma unroll
            for (int r = 0; r < 4; r++) {
                int row = m0 + wrow + mt*16 + quad*4 + r;
                int col = n0 + wcol + nt*16 + l15;
                if (swz) col = (col & ~31) | (((col & 12) << 1) | ((col & 16) >> 2) | (col & 3));
                C[(size_t)row * N + col] = (bf16)(acc[mt][nt][r] * alpha);
            }
}

// ---------------- flash4: single-pass, 64q/wave, kv-chunk 128, 1 block/CU ----------------
__launch_bounds__(256, 1)
__global__ void flash4_kernel(const bf16* __restrict__ q1, const bf16* __restrict__ q2,
                              const bf16* __restrict__ kbase, const bf16* __restrict__ vbase,
                              float* __restrict__ acc_out) {
    __shared__ __align__(16) bf16 Kt[2][128 * 72];    // [buf][kv][feat64 pad72]  36,864 B
    __shared__ __align__(16) bf16 Vt[2][128 * 136];   // [buf][c][kv128 pad136]   69,632 B
    int hx = blockIdx.x, qb = blockIdx.y;             // hx%8 -> XCD: (h&3)*2+s pinned
    int h = hx >> 1, s = hx & 1;
    const bf16* Q  = s ? q2 : q1;
    const bf16* Kp = kbase + (size_t)s * KQ * DFEAT + h * 64;
    const bf16* Vp = vbase + (size_t)s * KQ;          // row pitch 2*KQ (kv-swizzled cols)
    int t = threadIdx.x, lane = t & 63, wid = t >> 6;
    int quad = lane >> 4, l15 = lane & 15;
    int qbase = qb * 256 + wid * 64;

    // Q B-frags: 4 q-tiles x 2 k-chunks (persist)
    bf16x8 qf[4][2];
    #pragma unroll
    for (int mt = 0; mt < 4; mt++)
        #pragma unroll
        for (int ch = 0; ch < 2; ch++)
            qf[mt][ch] = *(const bf16x8*)(Q + (size_t)(qbase + mt*16 + l15) * DFEAT + h*64 + ch*32 + quad*8);

    // staging maps: K 128 rows x 2 halves (64B); V 128 rows x 2 halves (128B)
    int kr = t >> 1, ks = t & 1;
    const bf16* kg = Kp + (size_t)kr * DFEAT + ks * 32;
    bf16* kw0 = &Kt[0][kr * 72 + ks * 32];
    const bf16* vg = Vp + (size_t)kr * (2 * KQ) + ks * 64;
    bf16* vw0 = &Vt[0][kr * 136 + ks * 64];
    const int KWB = 128 * 72, VWB = 128 * 136;

    // prologue: stage chunk 0
    {
        #pragma unroll
        for (int j = 0; j < 4; j++) *(uint4*)(kw0 + j*8) = *(const uint4*)(kg + j*8);
        #pragma unroll
        for (int j = 0; j < 8; j++) *(uint4*)(vw0 + j*8) = *(const uint4*)(vg + j*8);
    }
    __syncthreads();

    f32x4 O[4][8] = {};
    float lrun[4] = {0.f, 0.f, 0.f, 0.f};

    for (int it = 0; it < KQ / 128; it++) {
        int p = it & 1;
        bool more = (it + 1 < KQ / 128);
        // prefetch next chunk into registers (consumed at the write below)
        uint4 kn[4], vn[8];
        if (more) {
            const bf16* kg2 = kg + (size_t)(it + 1) * 128 * DFEAT;
            const bf16* vg2 = vg + (size_t)(it + 1) * 128;
            #pragma unroll
            for (int j = 0; j < 4; j++) kn[j] = *(const uint4*)(kg2 + j*8);
            #pragma unroll
            for (int j = 0; j < 8; j++) vn[j] = *(const uint4*)(vg2 + j*8);
        }
        const bf16* Kb = &Kt[0][p * KWB];
        const bf16* Vb = &Vt[0][p * VWB];

        // QK -> exp2 -> packed P A-frags per 32-kv group
        bf16x8 Pf[4][4];
        #pragma unroll
        for (int g = 0; g < 4; g++) {
            bf16x8 ka0 = *(const bf16x8*)&Kb[((2*g)*16 + l15) * 72 + quad * 8];
            bf16x8 kb0 = *(const bf16x8*)&Kb[((2*g)*16 + l15) * 72 + 32 + quad * 8];
            bf16x8 ka1 = *(const bf16x8*)&Kb[((2*g+1)*16 + l15) * 72 + quad * 8];
            bf16x8 kb1 = *(const bf16x8*)&Kb[((2*g+1)*16 + l15) * 72 + 32 + quad * 8];
            #pragma unroll
            for (int mt = 0; mt < 4; mt++) {
                f32x4 s0 = {}, s1 = {};
                s0 = MFMA16(ka0, qf[mt][0], s0);
                s0 = MFMA16(kb0, qf[mt][1], s0);
                s1 = MFMA16(ka1, qf[mt][0], s1);
                s1 = MFMA16(kb1, qf[mt][1], s1);
                bf16x8 pp;
                float lsum = 0.f;
                #pragma unroll
                for (int r = 0; r < 4; r++) {
                    float e0 = exp2f(s0[r]);
                    float e1 = exp2f(s1[r]);
                    pp[r]     = (bf16)e0;
                    pp[4 + r] = (bf16)e1;
                    lsum += e0 + e1;
                }
                Pf[mt][g] = pp;
                lrun[mt] += lsum;
            }
        }
        // PV: O[q][c] += P . VW   (4 chained 32-kv groups)
        #pragma unroll
        for (int ct = 0; ct < 8; ct++) {
            #pragma unroll
            for (int g = 0; g < 4; g++) {
                bf16x8 vb = *(const bf16x8*)&Vb[(ct*16 + l15) * 136 + g*32 + quad * 8];
                #pragma unroll
                for (int mt = 0; mt < 4; mt++)
                    O[mt][ct] = MFMA16(Pf[mt][g], vb, O[mt][ct]);
            }
        }
        // write staged regs into the other buffer
        if (more) {
            bf16* kw = kw0 + (p ^ 1) * KWB;
            bf16* vw = vw0 + (p ^ 1) * VWB;
            #pragma unroll
            for (int j = 0; j < 4; j++) *(uint4*)(kw + j*8) = kn[j];
            #pragma unroll
            for (int j = 0; j < 8; j++) *(uint4*)(vw + j*8) = vn[j];
        }
        __syncthreads();
    }

    // l reduction across quads (lanes sharing l15), then normalized atomic combine over heads
    #pragma unroll
    for (int mt = 0; mt < 4; mt++) {
        lrun[mt] += __shfl_xor(lrun[mt], 16);
        lrun[mt] += __shfl_xor(lrun[mt], 32);
    }
    #pragma unroll
    for (int mt = 0; mt < 4; mt++)
        #pragma unroll
        for (int r = 0; r < 4; r++) {
            float lr = __shfl(lrun[mt], quad * 4 + r);
            float inv = 1.0f / (8.0f * lr);
            int row = qbase + mt*16 + quad*4 + r;
            #pragma unroll
            for (int ct = 0; ct < 8; ct++)
                atomicAdd(&acc_out[((size_t)s * N_Q + row) * NLAB + ct*16 + l15], O[mt][ct][r] * inv);
        }
}

// ---------------- bias + cast ----------------
__global__ void bias_kernel(const float* __restrict__ acc, const void* __restrict__ bo,
                            void* __restrict__ out, const int* __restrict__ modep) {
    int f32m = *modep;
    int idx = blockIdx.x * 256 + threadIdx.x;
    float v = acc[idx] + loads(bo, idx & (NLAB - 1), f32m);
    if (f32m) ((float*)out)[idx] = v;
    else      ((bf16*)out)[idx] = (bf16)v;
}

extern "C" void kernel_launch(void* const* d_in, const int* in_sizes, int n_in,
                              void* d_out, int out_size, void* d_ws, size_t ws_size,
                              hipStream_t stream) {
    const void* anchor   = d_in[0];
    const void* positive = d_in[1];
    const void* lbfeat   = d_in[2];
    const void* lboh     = d_in[3];
    const void* ulb1     = d_in[5];
    const void* ulb2     = d_in[6];
    const void* fq1i     = d_in[7];
    const void* fq2i     = d_in[8];
    const void* lq1i     = d_in[9];
    const void* lq2i     = d_in[10];
    const void* Wq       = d_in[11];
    const void* Wk       = d_in[12];
    const void* Wo       = d_in[13];
    const void* bo       = d_in[14];

    char* ws = (char*)d_ws;
    int*  counts = (int*)(ws + OFF_COUNTS);
    int*  modep  = (int*)(ws + OFF_MODE);
    int*  flags  = (int*)(ws + OFF_FLAGS);
    int*  sel    = (int*)(ws + OFF_SEL);
    bf16* fq1  = (bf16*)(ws + OFF_FQ1);
    bf16* fq2  = (bf16*)(ws + OFF_FQ2);
    bf16* lq1  = (bf16*)(ws + OFF_LQ1);
    bf16* lq2  = (bf16*)(ws + OFF_LQ2);
    bf16* q1   = (bf16*)(ws + OFF_Q1);
    bf16* q2   = (bf16*)(ws + OFF_Q2);
    bf16* k1   = (bf16*)(ws + OFF_K1);
    bf16* wqT  = (bf16*)(ws + OFF_WQT);
    bf16* wkT  = (bf16*)(ws + OFF_WKT);
    bf16* woT  = (bf16*)(ws + OFF_WOT);
    bf16* vwt  = (bf16*)(ws + OFF_VWT);
    float* accb = (float*)(ws + OFF_ACC);

    hipMemsetAsync(accb, 0, (size_t)2 * N_Q * NLAB * sizeof(float), stream);

    detect_kernel<<<1, 256, 0, stream>>>(anchor, modep);
    flag_kernel<<<dim3(N_Q, 2), 64, 0, stream>>>(ulb1, ulb2, flags, modep);
    scan_kernel<<<2, 1024, 0, stream>>>(flags, sel, counts);
    buildq_kernel<<<dim3(KQ, 2), 128, 0, stream>>>(anchor, positive, lbfeat, lboh, ulb1, ulb2,
                                                   fq1i, fq2i, lq1i, lq2i, sel, counts,
                                                   fq1, fq2, lq1, lq2, modep);
    transpose_kernel<<<dim3(16, 16, 3), 256, 0, stream>>>(Wq, Wk, Wo, wqT, wkT, woT, modep);

    // q = (x @ Wq) * dh^-0.5 * log2(e)  — both streams in one launch (z)
    const float qalpha = 0.125f * 1.44269504088896f;
    gemm_nt<<<dim3(32, 4, 2), 256, 0, stream>>>(anchor, positive, wqT, q1, q2,
                                                4096, 512, 512, qalpha, modep, 1, 0);
    // k = [fq1;fq2] @ Wk  (merged, M=16384)
    gemm_nt<<<dim3(128, 4, 1), 256, 0, stream>>>(fq1, nullptr, wkT, k1, nullptr,
                                                 16384, 512, 512, 1.0f, modep, 0, 0);
    // VW^T = Wo^T @ lq^T, merged N=16384, kv-swizzled columns
    gemm_nt<<<dim3(1, 128, 1), 256, 0, stream>>>(woT, nullptr, lq1, vwt, nullptr,
                                                 128, 16384, 128, 1.0f, modep, 0, 1);

    flash4_kernel<<<dim3(16, 16, 1), 256, 0, stream>>>(q1, q2, k1, vwt, accb);
    bias_kernel<<<(2 * N_Q * NLAB) / 256, 256, 0, stream>>>(accb, bo, d_out, modep);
}